// Round 5
// baseline (482.819 us; speedup 1.0000x reference)
//
#include <hip/hip_runtime.h>

typedef _Float16 f16;
typedef __attribute__((ext_vector_type(8))) _Float16 f16x8;
typedef __attribute__((ext_vector_type(4))) _Float16 f16x4;
typedef __attribute__((ext_vector_type(4))) float f32x4;
typedef __attribute__((ext_vector_type(16))) float f32x16;

// Problem constants
constexpr int BB = 8;
constexpr int NN = 2048;
constexpr int CC = 1024;
constexpr int MTOT = BB * NN;     // 16384
constexpr int KKEEP = 1638;

// ---------------------------------------------------------------------------
// async 16B global -> LDS (HW: dst = wave-uniform base + lane*16)
// ---------------------------------------------------------------------------
__device__ __forceinline__ void gl_lds16(const void* g, void* l) {
  __builtin_amdgcn_global_load_lds((__attribute__((address_space(1))) void*)g,
                                   (__attribute__((address_space(3))) void*)l,
                                   16, 0, 0);
}

// ---------------------------------------------------------------------------
// Unified fp32 -> fp16 conversion: x -> xb, {Wq,Wk,Wv} -> wqkv (concatenated)
// ---------------------------------------------------------------------------
constexpr int X4 = MTOT * CC / 4;   // 4,194,304 vec4
constexpr int W4 = CC * CC / 4;     // 262,144 vec4
__global__ __launch_bounds__(256) void cvt_all(
    const float* __restrict__ x, const float* __restrict__ Wq,
    const float* __restrict__ Wk, const float* __restrict__ Wv,
    f16* __restrict__ xb, f16* __restrict__ wqkv) {
  int i = blockIdx.x * 256 + threadIdx.x;
  const float* s;
  f16* d;
  if (i < X4) { s = x; d = xb; }
  else if (i < X4 + W4) { i -= X4; s = Wq; d = wqkv; }
  else if (i < X4 + 2 * W4) { i -= X4 + W4; s = Wk; d = wqkv + CC * CC; }
  else { i -= X4 + 2 * W4; s = Wv; d = wqkv + 2 * CC * CC; }
  float4 f = ((const float4*)s)[i];
  f16x4 o = {(f16)f.x, (f16)f.y, (f16)f.z, (f16)f.w};
  ((f16x4*)d)[i] = o;
}

// ---------------------------------------------------------------------------
// GEMM-BT core:  C[m][n] = sum_k A[m][k] * B[n][k]   (both operands k-contig)
// 128x128 tile, BK=64 (32 KB LDS), 256 threads = 4 waves (2x2), each wave
// 64x64 output.
//
// R5: MFMA shape 16x16x32 -> 32x32x16 (same total FLOP, measured pipe rate
// 2495 vs 2176 TF, m119; half the MFMA instruction count per K-tile: 16 big
// vs 32 small in the same barrier frame).  Per wave: 2x2 fragments of 32x32,
// acc[2][2] f32x16.
//   A/B fragment: row(col) = lane&31, k = (lane>>5)*8 + e   (e=0..7)
//   C/D:          col = lane&31, row = (reg&3) + 8*(reg>>2) + 4*(lane>>5)
//                 (HW-verified m74/m101; dtype-independent m121-128)
//
// LDS 3-bit row-XOR swizzle (unchanged): LDS slot s of row R holds global
// k-granule s ^ (R&7); staging pre-swizzles the GLOBAL source because
// global_load_lds writes linearly. Fragment read for k-granule c reads slot
// c ^ (lane&7): within each 16-lane LDS phase, lane&7 covers 0-7 twice ->
// 2 lanes per 16B slot group = 2-way = free (m136). SQ_LDS_BANK_CONFLICT=0.
//
// MODE 0: fp32 out, * scale, batched (score S and PV GEMMs); XCD-chunk
//         swizzle + nontemporal C stores (neutral but harmless, kept).
// MODE 3: fused QKV epilogue: cols [0,2048) -> f16 row-major QK (pitch 2048,
//         bias bq/bk), cols [2048,3072) -> f16 TRANSPOSED Vt[1024][MTOT] +bv.
// ---------------------------------------------------------------------------
template <int MODE>
__global__ __launch_bounds__(256, 2) void gemm_bt(
    const f16* __restrict__ A, const f16* __restrict__ B,
    const float* __restrict__ b0, const float* __restrict__ b1,
    const float* __restrict__ b2, void* __restrict__ Cout,
    void* __restrict__ Cout2, int K, int lda, int ldb, int ldc, float scale,
    long strideA, long strideB, long strideC) {
  int bxi, byi, bzi;
  if constexpr (MODE == 0) {
    // bijective XCD-chunk transform (nwg % 8 == 0 for both MODE-0 grids)
    const int gx = gridDim.x, gy = gridDim.y;
    const int per = gx * gy;
    const int nwg = per * gridDim.z;
    const int o = blockIdx.x + gx * (blockIdx.y + gy * blockIdx.z);
    const int qq = nwg >> 3;
    const int no = (o & 7) * qq + (o >> 3);
    bzi = no / per;
    const int rem = no - bzi * per;
    byi = rem % gy;
    bxi = rem / gy;
  } else {
    bxi = blockIdx.x; byi = blockIdx.y; bzi = blockIdx.z;
  }

  const f16* Ab = A + (size_t)bzi * strideA;
  const f16* Bbp = B + (size_t)bzi * strideB;

  const int bm = bxi * 128;
  const int bn = byi * 128;
  const int tid = threadIdx.x;
  const int wave = tid >> 6;
  const int lane = tid & 63;
  const int wy = wave >> 1, wx = wave & 1;

  __shared__ f16 As[128 * 64];
  __shared__ f16 Bs[128 * 64];

  f32x16 acc[2][2];
#pragma unroll
  for (int i = 0; i < 2; i++)
#pragma unroll
    for (int j = 0; j < 2; j++)
#pragma unroll
      for (int e = 0; e < 16; e++) acc[i][j][e] = 0.f;

  // staging: wave w covers tile rows [w*32, w*32+32), 4 insts x 8 rows.
  // lane l -> row (l>>3), loads global granule (l&7)^((l>>3)&7).
  const int sr = wave * 32 + (lane >> 3);
  const int gsrc = ((lane & 7) ^ ((lane >> 3) & 7)) * 8;
  const f16* gA0 = Ab + (size_t)(bm + sr) * lda + gsrc;
  const f16* gB0 = Bbp + (size_t)(bn + sr) * ldb + gsrc;
  f16* lA = As + (wave * 32) * 64 + lane * 8;  // == base + lane*16B
  f16* lB = Bs + (wave * 32) * 64 + lane * 8;

  // fragment coords (32x32x16): row/col = lane&31, k-half h = lane>>5.
  // K-tile of 64 = 4 mfma k-chunks; chunk kk covers k-granules h + 2*kk.
  // A[m][granule c] lives at LDS slot c ^ (m&7); m&7 == lane&7 here.
  const int il = lane & 31;
  const int h = lane >> 5;
  const int frm0 = wy * 64 + il;
  const int frn0 = wx * 64 + il;
  int gk[4];
#pragma unroll
  for (int kk = 0; kk < 4; kk++) gk[kk] = ((h + 2 * kk) ^ (lane & 7)) * 8;

  for (int k0 = 0; k0 < K; k0 += 64) {
#pragma unroll
    for (int r = 0; r < 4; r++) {
      gl_lds16(gA0 + (size_t)8 * r * lda + k0, lA + r * 512);
      gl_lds16(gB0 + (size_t)8 * r * ldb + k0, lB + r * 512);
    }
    __syncthreads();
    f16x8 av[4][2], bv[4][2];
#pragma unroll
    for (int kk = 0; kk < 4; kk++)
#pragma unroll
      for (int i = 0; i < 2; i++) {
        av[kk][i] = *(const f16x8*)(As + (frm0 + 32 * i) * 64 + gk[kk]);
        bv[kk][i] = *(const f16x8*)(Bs + (frn0 + 32 * i) * 64 + gk[kk]);
      }
#pragma unroll
    for (int kk = 0; kk < 4; kk++)
#pragma unroll
      for (int i = 0; i < 2; i++)
#pragma unroll
        for (int j = 0; j < 2; j++)
          acc[i][j] = __builtin_amdgcn_mfma_f32_32x32x16_f16(
              av[kk][i], bv[kk][j], acc[i][j], 0, 0, 0);
    __syncthreads();
  }

  // epilogue: C/D col = lane&31, row = (reg&3) + 8*(reg>>2) + 4*h
#pragma unroll
  for (int i = 0; i < 2; i++) {
#pragma unroll
    for (int j = 0; j < 2; j++) {
      const int col = bn + wx * 64 + j * 32 + il;
#pragma unroll
      for (int m = 0; m < 4; m++) {
        const int row0 = bm + wy * 64 + i * 32 + 8 * m + 4 * h;
        if (MODE == 0) {
          float* C = (float*)Cout + (size_t)bzi * strideC;
#pragma unroll
          for (int r = 0; r < 4; r++)
            __builtin_nontemporal_store(acc[i][j][4 * m + r] * scale,
                                        &C[(size_t)(row0 + r) * ldc + col]);
        } else {  // MODE 3 — region is uniform per block (bn multiple of 128)
          if (bn < 2048) {
            f16* C = (f16*)Cout;
            const float* bias = (bn < 1024) ? b0 : (b1 - 1024);
            const float bb = bias[col];
#pragma unroll
            for (int r = 0; r < 4; r++)
              C[(size_t)(row0 + r) * 2048 + col] = (f16)(acc[i][j][4 * m + r] + bb);
          } else {
            f16* C = (f16*)Cout2;
            const float bb = b2[col - 2048];
            f16x4 o;
#pragma unroll
            for (int r = 0; r < 4; r++) o[r] = (f16)(acc[i][j][4 * m + r] + bb);
            *(f16x4*)(C + (size_t)(col - 2048) * MTOT + row0) = o;
          }
        }
      }
    }
  }
}

// ---------------------------------------------------------------------------
// Per-row exact top-k(1638) + softmax — one wave per row, zero barriers.
// 256 threads = 4 independent waves, each owns one full row (32 f32/lane) and
// a private 1024-bin LDS histogram. All reductions are intra-wave shuffles;
// DS ops are per-wave in-order (lgkmcnt(0) guards at phase boundaries).
// Selection semantics: quantized histogram -> threshold bin -> exact tie
// refinement on fp32 value with ascending-index tie-break (== lax.top_k).
// ---------------------------------------------------------------------------
__global__ __launch_bounds__(256) void topk_softmax_kernel(
    const float* __restrict__ S, f16* __restrict__ P) {
  const int tid = threadIdx.x;
  const int wave = tid >> 6;
  const int lane = tid & 63;
  const size_t row = (size_t)blockIdx.x * 4 + wave;
  const float* srow = S + row * 2048;
  f16* prow = P + row * 2048;

  __shared__ int hist_s[4][1024];     // 16 KB
  __shared__ float cval_s[4][64];
  __shared__ int cidx_s[4][64];
  __shared__ int cnum_s[4];
  __shared__ int thr_s[4], want_s[4];
  int* hist = hist_s[wave];

  // load: element index = 4*lane + 256*r + c  (coalesced float4)
  float v[32];
#pragma unroll
  for (int r = 0; r < 8; r++) {
    float4 f = ((const float4*)srow)[lane + 64 * r];
    v[4 * r] = f.x; v[4 * r + 1] = f.y; v[4 * r + 2] = f.z; v[4 * r + 3] = f.w;
  }

  // zero private hist (256 int4) + counter
#pragma unroll
  for (int r = 0; r < 4; r++) ((int4*)hist)[lane + 64 * r] = (int4){0, 0, 0, 0};
  if (lane == 0) cnum_s[wave] = 0;

  // wave min/max
  float lo = v[0], hi = v[0];
#pragma unroll
  for (int j = 1; j < 32; j++) { lo = fminf(lo, v[j]); hi = fmaxf(hi, v[j]); }
#pragma unroll
  for (int off = 32; off > 0; off >>= 1) {
    lo = fminf(lo, __shfl_xor(lo, off, 64));
    hi = fmaxf(hi, __shfl_xor(hi, off, 64));
  }

  if (hi == lo) {  // degenerate row: uniform over first KKEEP
    const float w = 1.0f / (float)KKEEP;
#pragma unroll
    for (int r = 0; r < 8; r++) {
      const int e0 = 4 * lane + 256 * r;
      f16x4 o;
#pragma unroll
      for (int c = 0; c < 4; c++) o[c] = (f16)((e0 + c < KKEEP) ? w : 0.f);
      *(f16x4*)(prow + e0) = o;
    }
    return;
  }

  // histogram (private -> only intra-wave atomics)
  const float qs = 1024.0f / (hi - lo);
  asm volatile("s_waitcnt lgkmcnt(0)" ::: "memory");  // zeros committed
#pragma unroll
  for (int j = 0; j < 32; j++) {
    int k = (int)((v[j] - lo) * qs);
    k = (k > 1023) ? 1023 : k;
    atomicAdd(&hist[k], 1);
  }
  asm volatile("s_waitcnt lgkmcnt(0)" ::: "memory");  // atomics committed

  // suffix scan over 1024 bins: lane owns bins [16*lane, 16*lane+16)
  int h[16];
#pragma unroll
  for (int r = 0; r < 4; r++) {
    int4 t4 = ((const int4*)hist)[4 * lane + r];
    h[4 * r] = t4.x; h[4 * r + 1] = t4.y; h[4 * r + 2] = t4.z; h[4 * r + 3] = t4.w;
  }
  int s[16];
  s[15] = h[15];
#pragma unroll
  for (int j = 14; j >= 0; j--) s[j] = s[j + 1] + h[j];
  const int partial = s[0];
  int sfx = partial;
#pragma unroll
  for (int off = 1; off < 64; off <<= 1) {
    int o = __shfl_down(sfx, off, 64);
    sfx += (lane + off < 64) ? o : 0;
  }
  const int base = sfx - partial;  // count in bins owned by higher lanes
#pragma unroll
  for (int j = 0; j < 16; j++) {
    const int cum = s[j] + base;       // count of elements in bins >= this bin
    const int above = cum - h[j];      // count strictly above this bin
    if (cum >= KKEEP && above < KKEEP) {
      thr_s[wave] = 16 * lane + j;
      want_s[wave] = KKEEP - above;
    }
  }
  asm volatile("s_waitcnt lgkmcnt(0)" ::: "memory");
  const int thr = thr_s[wave];
  const int wantin = want_s[wave];

  // collect threshold-bin candidates (expected ~2 with 1024 bins; cap 64)
#pragma unroll
  for (int j = 0; j < 32; j++) {
    int k = (int)((v[j] - lo) * qs);
    k = (k > 1023) ? 1023 : k;
    if (k == thr) {
      int slot = atomicAdd(&cnum_s[wave], 1);
      if (slot < 64) {
        cval_s[wave][slot] = v[j];
        cidx_s[wave][slot] = 4 * lane + 256 * (j >> 2) + (j & 3);
      }
    }
  }
  asm volatile("s_waitcnt lgkmcnt(0)" ::: "memory");
  const int n = (cnum_s[wave] < 64) ? cnum_s[wave] : 64;

  // classify + exp + wave sum
  float lsum = 0.f;
#pragma unroll
  for (int j = 0; j < 32; j++) {
    int k = (int)((v[j] - lo) * qs);
    k = (k > 1023) ? 1023 : k;
    bool kept;
    if (k > thr) {
      kept = true;
    } else if (k < thr) {
      kept = false;
    } else {
      const int myidx = 4 * lane + 256 * (j >> 2) + (j & 3);
      int rank = 0;
      for (int c = 0; c < n; c++) {
        const float cv = cval_s[wave][c];
        rank += (cv > v[j] || (cv == v[j] && cidx_s[wave][c] < myidx)) ? 1 : 0;
      }
      kept = rank < wantin;
    }
    const float e = kept ? __expf(v[j] - hi) : 0.f;
    v[j] = e;
    lsum += e;
  }
#pragma unroll
  for (int off = 32; off > 0; off >>= 1) lsum += __shfl_xor(lsum, off, 64);
  const float inv = 1.0f / lsum;

#pragma unroll
  for (int r = 0; r < 8; r++) {
    f16x4 o;
#pragma unroll
    for (int c = 0; c < 4; c++) o[c] = (f16)(v[4 * r + c] * inv);
    *(f16x4*)(prow + 4 * lane + 256 * r) = o;
  }
}

// ---------------------------------------------------------------------------
// launch — 5 dispatches.
// Workspace (peak 224 MiB): [qkb 64M][vtb 32M][S fp32 128M]
//   qkb = [16384][2048] f16: cols 0-1023 Q, 1024-2047 K.
//   xb (32M) + wqkv (6M) aliased into S's span (dead before S written).
//   Pc (compact f16 P, 64M) aliased over qkb (dead after score GEMM).
// ---------------------------------------------------------------------------
extern "C" void kernel_launch(void* const* d_in, const int* in_sizes, int n_in,
                              void* d_out, int out_size, void* d_ws, size_t ws_size,
                              hipStream_t stream) {
  (void)in_sizes; (void)n_in; (void)out_size; (void)ws_size;
  const float* x = (const float*)d_in[0];
  const float* Wq = (const float*)d_in[1];
  const float* bq = (const float*)d_in[2];
  const float* Wk = (const float*)d_in[3];
  const float* bk = (const float*)d_in[4];
  const float* Wv = (const float*)d_in[5];
  const float* bv = (const float*)d_in[6];
  float* out = (float*)d_out;

  char* ws = (char*)d_ws;
  f16* qkb = (f16*)(ws + 0);           // [16384][2048] f16  67,108,864 B
  f16* vtb = (f16*)(ws + 67108864);    // [1024][16384] f16 (V^T)
  float* S = (float*)(ws + 100663296); // [8][2048][2048] fp32 (134,217,728 B)
  // --- aliased into S's span; dead before S is first written ---
  f16* xb = (f16*)(ws + 100663296);    // [16384][1024]
  f16* wqkv = (f16*)(ws + 134217728);  // [3072][1024] (Wq|Wk|Wv rows)
  // --- aliased over qkb; dead after the score GEMM ---
  f16* Pc = (f16*)(ws + 0);            // [8][2048][2048] f16 compact

  // 1) conversions (single dispatch)
  cvt_all<<<(X4 + 3 * W4 + 255) / 256, 256, 0, stream>>>(x, Wq, Wk, Wv, xb, wqkv);

  // 2) fused QKV projection: cols 0-2047 -> qkb, cols 2048-3071 -> vtb (transposed)
  gemm_bt<3><<<dim3(MTOT / 128, 3072 / 128, 1), 256, 0, stream>>>(
      xb, wqkv, bq, bk, bv, qkb, vtb, CC, CC, CC, 0, 1.f, 0, 0, 0);

  // 3) scores S[b] = Q[b] K[b]^T / 32  (fp32 out; overwrites dead xb/wqkv)
  gemm_bt<0><<<dim3(NN / 128, NN / 128, BB), 256, 0, stream>>>(
      qkb, qkb + 1024, nullptr, nullptr, nullptr, S, nullptr, CC, 2048, 2048, NN,
      1.f / 32.f, (long)NN * 2048, (long)NN * 2048, (long)NN * NN);

  // 4) exact top-k + softmax -> compact P f16 (over dead qkb; barrier-free)
  topk_softmax_kernel<<<MTOT / 4, 256, 0, stream>>>(S, Pc);

  // 5) O[b] = P[b] Vt[b]^T  (fp32 out to d_out)
  gemm_bt<0><<<dim3(NN / 128, CC / 128, BB), 256, 0, stream>>>(
      Pc, vtb, nullptr, nullptr, nullptr, out, nullptr, NN, NN, MTOT, CC, 1.f,
      (long)NN * NN, (long)NN, (long)NN * CC);
}

// Round 6
// 456.848 us; speedup vs baseline: 1.0568x; 1.0568x over previous
//
#include <hip/hip_runtime.h>

typedef _Float16 f16;
typedef __attribute__((ext_vector_type(8))) _Float16 f16x8;
typedef __attribute__((ext_vector_type(4))) _Float16 f16x4;
typedef __attribute__((ext_vector_type(4))) float f32x4;

// Problem constants
constexpr int BB = 8;
constexpr int NN = 2048;
constexpr int CC = 1024;
constexpr int MTOT = BB * NN;     // 16384
constexpr int KKEEP = 1638;

// ---------------------------------------------------------------------------
// async 16B global -> LDS (HW: dst = wave-uniform base + lane*16)
// ---------------------------------------------------------------------------
__device__ __forceinline__ void gl_lds16(const void* g, void* l) {
  __builtin_amdgcn_global_load_lds((__attribute__((address_space(1))) void*)g,
                                   (__attribute__((address_space(3))) void*)l,
                                   16, 0, 0);
}

// ---------------------------------------------------------------------------
// Unified fp32 -> fp16 conversion: x -> xb, {Wq,Wk,Wv} -> wqkv (concatenated)
// ---------------------------------------------------------------------------
constexpr int X4 = MTOT * CC / 4;   // 4,194,304 vec4
constexpr int W4 = CC * CC / 4;     // 262,144 vec4
__global__ __launch_bounds__(256) void cvt_all(
    const float* __restrict__ x, const float* __restrict__ Wq,
    const float* __restrict__ Wk, const float* __restrict__ Wv,
    f16* __restrict__ xb, f16* __restrict__ wqkv) {
  int i = blockIdx.x * 256 + threadIdx.x;
  const float* s;
  f16* d;
  if (i < X4) { s = x; d = xb; }
  else if (i < X4 + W4) { i -= X4; s = Wq; d = wqkv; }
  else if (i < X4 + 2 * W4) { i -= X4 + W4; s = Wk; d = wqkv + CC * CC; }
  else { i -= X4 + 2 * W4; s = Wv; d = wqkv + 2 * CC * CC; }
  float4 f = ((const float4*)s)[i];
  f16x4 o = {(f16)f.x, (f16)f.y, (f16)f.z, (f16)f.w};
  ((f16x4*)d)[i] = o;
}

// ---------------------------------------------------------------------------
// GEMM-BT core:  C[m][n] = sum_k A[m][k] * B[n][k]   (both operands k-contig)
// 128x128 tile, BK=64 (32 KB LDS), 256 threads = 4 waves (2x2), each wave
// 64x64 = 4x4 fragments of mfma_f32_16x16x32_f16, 32 MFMA per barrier pair.
// Best-measured configuration (421.5 us total; QKV 118.6 us = 875 TF,
// MfmaUtil ~40%, SQ_LDS_BANK_CONFLICT = 0).
//
// LDS 3-bit row-XOR swizzle: rows are 64 f16 = exactly 32 banks, so all
// rows alias bank-identically. global_load_lds pins LDS dst = base + lane*16,
// so we permute the SOURCE: LDS slot s of row R holds global k-granule
// s ^ (R&7). Staging lane l (row l>>3, slot l&7) therefore loads granule
// (l&7) ^ ((l>>3)&7). Fragment reads address slot (q+4kk) ^ (m&7); since
// m&7 == id&7, each consecutive-lane octet (fixed q, id 0..7) covers all 8
// bank-groups -> conflict-free ds_read_b128 phases.
// NOTE (R5 lesson): this swizzle is structurally matched to 16x16 fragments
// (16-row column reads split across lane-quarters). 32x32 fragments read 32
// rows at one slot each -> unavoidable 4-way alias within 8 slots at 128B
// row pitch (measured 1.26e7 conflicts, -20%). Do not switch MFMA shape
// without redesigning the LDS geometry.
//
// MODE 0: fp32 out, * scale, batched (score S and PV GEMMs). Plain stores:
// S is re-read by topk and fits in L3 (128 MB < 256 MB) — NT hints on S
// defeat that reuse (R4 lesson). No XCD remap: measured neutral.
// MODE 3: fused QKV epilogue: cols [0,2048) -> f16 row-major QK (pitch 2048,
//         bias bq/bk), cols [2048,3072) -> f16 TRANSPOSED Vt[1024][MTOT] +bv.
// ---------------------------------------------------------------------------
template <int MODE>
__global__ __launch_bounds__(256, 2) void gemm_bt(
    const f16* __restrict__ A, const f16* __restrict__ B,
    const float* __restrict__ b0, const float* __restrict__ b1,
    const float* __restrict__ b2, void* __restrict__ Cout,
    void* __restrict__ Cout2, int K, int lda, int ldb, int ldc, float scale,
    long strideA, long strideB, long strideC) {
  const f16* Ab = A + (size_t)blockIdx.z * strideA;
  const f16* Bbp = B + (size_t)blockIdx.z * strideB;

  const int bm = blockIdx.x * 128;
  const int bn = blockIdx.y * 128;
  const int tid = threadIdx.x;
  const int wave = tid >> 6;
  const int lane = tid & 63;
  const int wy = wave >> 1, wx = wave & 1;

  __shared__ f16 As[128 * 64];
  __shared__ f16 Bs[128 * 64];

  f32x4 acc[4][4];
#pragma unroll
  for (int i = 0; i < 4; i++)
#pragma unroll
    for (int j = 0; j < 4; j++) acc[i][j] = (f32x4){0.f, 0.f, 0.f, 0.f};

  // staging: wave w covers tile rows [w*32, w*32+32), 4 insts x 8 rows.
  // lane l -> row (l>>3), loads global granule (l&7)^((l>>3)&7).
  const int sr = wave * 32 + (lane >> 3);
  const int gsrc = ((lane & 7) ^ ((lane >> 3) & 7)) * 8;
  const f16* gA0 = Ab + (size_t)(bm + sr) * lda + gsrc;
  const f16* gB0 = Bbp + (size_t)(bn + sr) * ldb + gsrc;
  f16* lA = As + (wave * 32) * 64 + lane * 8;  // == base + lane*16B
  f16* lB = Bs + (wave * 32) * 64 + lane * 8;

  // fragment coords: A[m][k granule q+4kk] lives at LDS slot (q+4kk)^(m&7)
  const int id = lane & 15;
  const int q = lane >> 4;
  const int frm0 = wy * 64 + id;
  const int frn0 = wx * 64 + id;
  const int g0 = (q ^ (id & 7)) * 8;        // slot offset (f16) for kk=0
  const int g1 = ((q + 4) ^ (id & 7)) * 8;  // for kk=1

  for (int k0 = 0; k0 < K; k0 += 64) {
#pragma unroll
    for (int r = 0; r < 4; r++) {
      gl_lds16(gA0 + (size_t)8 * r * lda + k0, lA + r * 512);
      gl_lds16(gB0 + (size_t)8 * r * ldb + k0, lB + r * 512);
    }
    __syncthreads();
    f16x8 av[2][4], bv[2][4];
#pragma unroll
    for (int i = 0; i < 4; i++) {
      av[0][i] = *(const f16x8*)(As + (frm0 + 16 * i) * 64 + g0);
      av[1][i] = *(const f16x8*)(As + (frm0 + 16 * i) * 64 + g1);
      bv[0][i] = *(const f16x8*)(Bs + (frn0 + 16 * i) * 64 + g0);
      bv[1][i] = *(const f16x8*)(Bs + (frn0 + 16 * i) * 64 + g1);
    }
#pragma unroll
    for (int kk = 0; kk < 2; kk++)
#pragma unroll
      for (int i = 0; i < 4; i++)
#pragma unroll
        for (int j = 0; j < 4; j++)
          acc[i][j] = __builtin_amdgcn_mfma_f32_16x16x32_f16(av[kk][i], bv[kk][j],
                                                             acc[i][j], 0, 0, 0);
    __syncthreads();
  }

  // epilogue: C/D layout col=lane&15, row=(lane>>4)*4 + r
  const int ci = id;
#pragma unroll
  for (int i = 0; i < 4; i++) {
#pragma unroll
    for (int j = 0; j < 4; j++) {
      const int row0 = bm + wy * 64 + i * 16 + q * 4;
      const int col = bn + wx * 64 + j * 16 + ci;
      if (MODE == 0) {
        float* C = (float*)Cout + (size_t)blockIdx.z * strideC;
#pragma unroll
        for (int r = 0; r < 4; r++)
          C[(size_t)(row0 + r) * ldc + col] = acc[i][j][r] * scale;
      } else {  // MODE 3 — region is uniform per block (bn multiple of 128)
        if (bn < 2048) {
          f16* C = (f16*)Cout;
          const float* bias = (bn < 1024) ? b0 : (b1 - 1024);
          const float bb = bias[col];
#pragma unroll
          for (int r = 0; r < 4; r++)
            C[(size_t)(row0 + r) * 2048 + col] = (f16)(acc[i][j][r] + bb);
        } else {
          f16* C = (f16*)Cout2;
          const float bb = b2[col - 2048];
          f16x4 o;
#pragma unroll
          for (int r = 0; r < 4; r++) o[r] = (f16)(acc[i][j][r] + bb);
          *(f16x4*)(C + (size_t)(col - 2048) * MTOT + row0) = o;
        }
      }
    }
  }
}

// ---------------------------------------------------------------------------
// Per-row exact top-k(1638) + softmax (R0 block-level version — part of the
// best-measured 421.5 us configuration; the wave-per-row rewrite measured
// ~+30 us total in R3/R4 and was reverted).
// Quantized 2048-bin histogram -> threshold bin -> exact tie refinement on
// fp32 value + index. Reads fp32 S (pitch 2048), writes compact f16 P.
// ---------------------------------------------------------------------------
__global__ __launch_bounds__(256) void topk_softmax_kernel(
    const float* __restrict__ S, f16* __restrict__ P) {
  const size_t row = blockIdx.x;
  const float* srow = S + row * 2048;
  f16* prow = P + row * 2048;
  const int t = threadIdx.x;
  const int lane = t & 63;
  const int wave = t >> 6;

  float v[8];
  float4 f0 = ((const float4*)srow)[2 * t];
  float4 f1 = ((const float4*)srow)[2 * t + 1];
  v[0] = f0.x; v[1] = f0.y; v[2] = f0.z; v[3] = f0.w;
  v[4] = f1.x; v[5] = f1.y; v[6] = f1.z; v[7] = f1.w;

  __shared__ float wlo[4], whi[4];
  __shared__ float wf[4];
  __shared__ int wagg[4];
  __shared__ int hist[2048];
  __shared__ float cval[128];
  __shared__ int cidx[128];
  __shared__ int cnum;
  __shared__ int sh_thr, sh_want;

  float lo = v[0], hi = v[0];
#pragma unroll
  for (int j = 1; j < 8; j++) { lo = fminf(lo, v[j]); hi = fmaxf(hi, v[j]); }
#pragma unroll
  for (int off = 32; off > 0; off >>= 1) {
    lo = fminf(lo, __shfl_xor(lo, off, 64));
    hi = fmaxf(hi, __shfl_xor(hi, off, 64));
  }
  if (lane == 0) { wlo[wave] = lo; whi[wave] = hi; }
  if (t == 0) cnum = 0;
  ((int4*)hist)[2 * t] = (int4){0, 0, 0, 0};
  ((int4*)hist)[2 * t + 1] = (int4){0, 0, 0, 0};
  __syncthreads();
  lo = fminf(fminf(wlo[0], wlo[1]), fminf(wlo[2], wlo[3]));
  hi = fmaxf(fmaxf(whi[0], whi[1]), fmaxf(whi[2], whi[3]));

  if (hi == lo) {
    const float w = 1.0f / (float)KKEEP;
    f16x8 o;
#pragma unroll
    for (int j = 0; j < 8; j++) o[j] = (f16)((t * 8 + j < KKEEP) ? w : 0.f);
    *(f16x8*)(prow + t * 8) = o;
    return;
  }

  const float qs = 2048.0f / (hi - lo);
  int key[8];
#pragma unroll
  for (int j = 0; j < 8; j++) {
    int k = (int)((v[j] - lo) * qs);
    key[j] = (k > 2047) ? 2047 : k;
  }
#pragma unroll
  for (int j = 0; j < 8; j++) atomicAdd(&hist[key[j]], 1);
  __syncthreads();

  int4 h0 = ((const int4*)hist)[2 * t];
  int4 h1 = ((const int4*)hist)[2 * t + 1];
  int h[8] = {h0.x, h0.y, h0.z, h0.w, h1.x, h1.y, h1.z, h1.w};
  int s[8];
  s[7] = h[7];
#pragma unroll
  for (int j = 6; j >= 0; j--) s[j] = s[j + 1] + h[j];
  const int partial = s[0];
  int sfx = partial;
#pragma unroll
  for (int off = 1; off < 64; off <<= 1) {
    int o = __shfl_down(sfx, off, 64);
    sfx += (lane + off < 64) ? o : 0;
  }
  if (lane == 0) wagg[wave] = sfx;
  __syncthreads();
  int hiw = 0;
#pragma unroll
  for (int w = 0; w < 4; w++) hiw += (w > wave) ? wagg[w] : 0;
  const int base = (sfx - partial) + hiw;
#pragma unroll
  for (int j = 0; j < 8; j++) {
    const int cum = s[j] + base;
    const int above = cum - h[j];
    if (cum >= KKEEP && above < KKEEP) {
      sh_thr = 8 * t + j;
      sh_want = KKEEP - above;
    }
  }
  __syncthreads();
  const int thr = sh_thr;
  const int wantin = sh_want;

#pragma unroll
  for (int j = 0; j < 8; j++) {
    if (key[j] == thr) {
      int slot = atomicAdd(&cnum, 1);
      if (slot < 128) { cval[slot] = v[j]; cidx[slot] = t * 8 + j; }
    }
  }
  __syncthreads();
  const int n = (cnum < 128) ? cnum : 128;

  float e[8];
  float lsum = 0.f;
#pragma unroll
  for (int j = 0; j < 8; j++) {
    bool kept;
    if (key[j] > thr) {
      kept = true;
    } else if (key[j] < thr) {
      kept = false;
    } else {
      const int myidx = t * 8 + j;
      int rank = 0;
      for (int c = 0; c < n; c++) {
        const float cv = cval[c];
        rank += (cv > v[j] || (cv == v[j] && cidx[c] < myidx)) ? 1 : 0;
      }
      kept = rank < wantin;
    }
    e[j] = kept ? __expf(v[j] - hi) : 0.f;
    lsum += e[j];
  }
#pragma unroll
  for (int off = 32; off > 0; off >>= 1) lsum += __shfl_xor(lsum, off, 64);
  if (lane == 0) wf[wave] = lsum;
  __syncthreads();
  const float inv = 1.0f / (wf[0] + wf[1] + wf[2] + wf[3]);

  f16x8 o;
#pragma unroll
  for (int j = 0; j < 8; j++) o[j] = (f16)(e[j] * inv);
  *(f16x8*)(prow + t * 8) = o;
}

// ---------------------------------------------------------------------------
// launch — 5 dispatches.
// Workspace (peak 224 MiB): [qkb 64M][vtb 32M][S fp32 128M]
//   qkb = [16384][2048] f16: cols 0-1023 Q, 1024-2047 K.
//   xb (32M) + wqkv (6M) aliased into S's span (dead before S written).
//   Pc (compact f16 P, 64M) aliased over qkb (dead after score GEMM).
// ---------------------------------------------------------------------------
extern "C" void kernel_launch(void* const* d_in, const int* in_sizes, int n_in,
                              void* d_out, int out_size, void* d_ws, size_t ws_size,
                              hipStream_t stream) {
  (void)in_sizes; (void)n_in; (void)out_size; (void)ws_size;
  const float* x = (const float*)d_in[0];
  const float* Wq = (const float*)d_in[1];
  const float* bq = (const float*)d_in[2];
  const float* Wk = (const float*)d_in[3];
  const float* bk = (const float*)d_in[4];
  const float* Wv = (const float*)d_in[5];
  const float* bv = (const float*)d_in[6];
  float* out = (float*)d_out;

  char* ws = (char*)d_ws;
  f16* qkb = (f16*)(ws + 0);           // [16384][2048] f16  67,108,864 B
  f16* vtb = (f16*)(ws + 67108864);    // [1024][16384] f16 (V^T)
  float* S = (float*)(ws + 100663296); // [8][2048][2048] fp32 (134,217,728 B)
  // --- aliased into S's span; dead before S is first written ---
  f16* xb = (f16*)(ws + 100663296);    // [16384][1024]
  f16* wqkv = (f16*)(ws + 134217728);  // [3072][1024] (Wq|Wk|Wv rows)
  // --- aliased over qkb; dead after the score GEMM ---
  f16* Pc = (f16*)(ws + 0);            // [8][2048][2048] f16 compact

  // 1) conversions (single dispatch)
  cvt_all<<<(X4 + 3 * W4 + 255) / 256, 256, 0, stream>>>(x, Wq, Wk, Wv, xb, wqkv);

  // 2) fused QKV projection: cols 0-2047 -> qkb, cols 2048-3071 -> vtb (transposed)
  gemm_bt<3><<<dim3(MTOT / 128, 3072 / 128, 1), 256, 0, stream>>>(
      xb, wqkv, bq, bk, bv, qkb, vtb, CC, CC, CC, 0, 1.f, 0, 0, 0);

  // 3) scores S[b] = Q[b] K[b]^T / 32  (fp32 out; overwrites dead xb/wqkv)
  gemm_bt<0><<<dim3(NN / 128, NN / 128, BB), 256, 0, stream>>>(
      qkb, qkb + 1024, nullptr, nullptr, nullptr, S, nullptr, CC, 2048, 2048, NN,
      1.f / 32.f, (long)NN * 2048, (long)NN * 2048, (long)NN * NN);

  // 4) exact top-k + softmax -> compact P f16 (over dead qkb)
  topk_softmax_kernel<<<MTOT, 256, 0, stream>>>(S, Pc);

  // 5) O[b] = P[b] Vt[b]^T  (fp32 out to d_out)
  gemm_bt<0><<<dim3(NN / 128, CC / 128, BB), 256, 0, stream>>>(
      Pc, vtb, nullptr, nullptr, nullptr, out, nullptr, NN, NN, MTOT, CC, 1.f,
      (long)NN * NN, (long)NN, (long)NN * CC);
}

// Round 7
// 448.055 us; speedup vs baseline: 1.0776x; 1.0196x over previous
//
#include <hip/hip_runtime.h>

typedef _Float16 f16;
typedef __attribute__((ext_vector_type(8))) _Float16 f16x8;
typedef __attribute__((ext_vector_type(4))) _Float16 f16x4;
typedef __attribute__((ext_vector_type(4))) float f32x4;

// Problem constants
constexpr int BB = 8;
constexpr int NN = 2048;
constexpr int CC = 1024;
constexpr int MTOT = BB * NN;     // 16384
constexpr int KKEEP = 1638;

// ---------------------------------------------------------------------------
// async 16B global -> LDS (HW: dst = wave-uniform base + lane*16)
// ---------------------------------------------------------------------------
__device__ __forceinline__ void gl_lds16(const void* g, void* l) {
  __builtin_amdgcn_global_load_lds((__attribute__((address_space(1))) void*)g,
                                   (__attribute__((address_space(3))) void*)l,
                                   16, 0, 0);
}

// ---------------------------------------------------------------------------
// Unified fp32 -> fp16 conversion: x -> xb, {Wq,Wk,Wv} -> wqkv (concatenated)
// ---------------------------------------------------------------------------
constexpr int X4 = MTOT * CC / 4;   // 4,194,304 vec4
constexpr int W4 = CC * CC / 4;     // 262,144 vec4
__global__ __launch_bounds__(256) void cvt_all(
    const float* __restrict__ x, const float* __restrict__ Wq,
    const float* __restrict__ Wk, const float* __restrict__ Wv,
    f16* __restrict__ xb, f16* __restrict__ wqkv) {
  int i = blockIdx.x * 256 + threadIdx.x;
  const float* s;
  f16* d;
  if (i < X4) { s = x; d = xb; }
  else if (i < X4 + W4) { i -= X4; s = Wq; d = wqkv; }
  else if (i < X4 + 2 * W4) { i -= X4 + W4; s = Wk; d = wqkv + CC * CC; }
  else { i -= X4 + 2 * W4; s = Wv; d = wqkv + 2 * CC * CC; }
  float4 f = ((const float4*)s)[i];
  f16x4 o = {(f16)f.x, (f16)f.y, (f16)f.z, (f16)f.w};
  ((f16x4*)d)[i] = o;
}

// ---------------------------------------------------------------------------
// GEMM-BT core:  C[m][n] = sum_k A[m][k] * B[n][k]   (both operands k-contig)
// 128x128 tile, BK=64 (32 KB LDS), 256 threads = 4 waves (2x2), each wave
// 64x64 = 4x4 fragments of mfma_f32_16x16x32_f16, 32 MFMA per barrier pair.
//
// R7: __launch_bounds__(256, 4). Counters showed Occupancy ~36% = 3 blocks/CU
// while resources allow 4 (LDS 32KBx4 <= 160KB; regs need <=128/wave unified:
// 64 VGPR measured + 64 AGPR acc = exactly 128 — the old (256,2) hint let
// regalloc use slack AGPRs, capping at 3 blocks). The structure's documented
// stall is the per-K-step barrier drain, hideable only by OTHER blocks'
// waves (m114) -> a 4th resident block attacks exactly that.
//
// LDS 3-bit row-XOR swizzle: rows are 64 f16 = exactly 32 banks, so all
// rows alias bank-identically. global_load_lds pins LDS dst = base + lane*16,
// so we permute the SOURCE: LDS slot s of row R holds global k-granule
// s ^ (R&7). Staging lane l (row l>>3, slot l&7) therefore loads granule
// (l&7) ^ ((l>>3)&7). Fragment reads address slot (q+4kk) ^ (m&7); since
// m&7 == id&7, each consecutive-lane octet (fixed q, id 0..7) covers all 8
// bank-groups -> conflict-free ds_read_b128 phases (SQ_LDS_BANK_CONFLICT=0).
// NOTE (R5 lesson): swizzle is matched to 16x16 fragments; 32x32 fragments
// alias 4-way (measured 1.26e7 conflicts, -20%). Don't switch MFMA shape.
//
// MODE 0: fp32 out, * scale, batched (score S and PV GEMMs). Plain stores:
// S is re-read by topk and fits in L3 — NT hints defeat that reuse (R4).
// MODE 3: fused QKV epilogue: cols [0,2048) -> f16 row-major QK (pitch 2048,
//         bias bq/bk), cols [2048,3072) -> f16 TRANSPOSED Vt[1024][MTOT] +bv.
// ---------------------------------------------------------------------------
template <int MODE>
__global__ __launch_bounds__(256, 4) void gemm_bt(
    const f16* __restrict__ A, const f16* __restrict__ B,
    const float* __restrict__ b0, const float* __restrict__ b1,
    const float* __restrict__ b2, void* __restrict__ Cout,
    void* __restrict__ Cout2, int K, int lda, int ldb, int ldc, float scale,
    long strideA, long strideB, long strideC) {
  const f16* Ab = A + (size_t)blockIdx.z * strideA;
  const f16* Bbp = B + (size_t)blockIdx.z * strideB;

  const int bm = blockIdx.x * 128;
  const int bn = blockIdx.y * 128;
  const int tid = threadIdx.x;
  const int wave = tid >> 6;
  const int lane = tid & 63;
  const int wy = wave >> 1, wx = wave & 1;

  __shared__ f16 As[128 * 64];
  __shared__ f16 Bs[128 * 64];

  f32x4 acc[4][4];
#pragma unroll
  for (int i = 0; i < 4; i++)
#pragma unroll
    for (int j = 0; j < 4; j++) acc[i][j] = (f32x4){0.f, 0.f, 0.f, 0.f};

  // staging: wave w covers tile rows [w*32, w*32+32), 4 insts x 8 rows.
  // lane l -> row (l>>3), loads global granule (l&7)^((l>>3)&7).
  const int sr = wave * 32 + (lane >> 3);
  const int gsrc = ((lane & 7) ^ ((lane >> 3) & 7)) * 8;
  const f16* gA0 = Ab + (size_t)(bm + sr) * lda + gsrc;
  const f16* gB0 = Bbp + (size_t)(bn + sr) * ldb + gsrc;
  f16* lA = As + (wave * 32) * 64 + lane * 8;  // == base + lane*16B
  f16* lB = Bs + (wave * 32) * 64 + lane * 8;

  // fragment coords: A[m][k granule q+4kk] lives at LDS slot (q+4kk)^(m&7)
  const int id = lane & 15;
  const int q = lane >> 4;
  const int frm0 = wy * 64 + id;
  const int frn0 = wx * 64 + id;
  const int g0 = (q ^ (id & 7)) * 8;        // slot offset (f16) for kk=0
  const int g1 = ((q + 4) ^ (id & 7)) * 8;  // for kk=1

  for (int k0 = 0; k0 < K; k0 += 64) {
#pragma unroll
    for (int r = 0; r < 4; r++) {
      gl_lds16(gA0 + (size_t)8 * r * lda + k0, lA + r * 512);
      gl_lds16(gB0 + (size_t)8 * r * ldb + k0, lB + r * 512);
    }
    __syncthreads();
    f16x8 av[2][4], bv[2][4];
#pragma unroll
    for (int i = 0; i < 4; i++) {
      av[0][i] = *(const f16x8*)(As + (frm0 + 16 * i) * 64 + g0);
      av[1][i] = *(const f16x8*)(As + (frm0 + 16 * i) * 64 + g1);
      bv[0][i] = *(const f16x8*)(Bs + (frn0 + 16 * i) * 64 + g0);
      bv[1][i] = *(const f16x8*)(Bs + (frn0 + 16 * i) * 64 + g1);
    }
#pragma unroll
    for (int kk = 0; kk < 2; kk++)
#pragma unroll
      for (int i = 0; i < 4; i++)
#pragma unroll
        for (int j = 0; j < 4; j++)
          acc[i][j] = __builtin_amdgcn_mfma_f32_16x16x32_f16(av[kk][i], bv[kk][j],
                                                             acc[i][j], 0, 0, 0);
    __syncthreads();
  }

  // epilogue: C/D layout col=lane&15, row=(lane>>4)*4 + r
  const int ci = id;
#pragma unroll
  for (int i = 0; i < 4; i++) {
#pragma unroll
    for (int j = 0; j < 4; j++) {
      const int row0 = bm + wy * 64 + i * 16 + q * 4;
      const int col = bn + wx * 64 + j * 16 + ci;
      if (MODE == 0) {
        float* C = (float*)Cout + (size_t)blockIdx.z * strideC;
#pragma unroll
        for (int r = 0; r < 4; r++)
          C[(size_t)(row0 + r) * ldc + col] = acc[i][j][r] * scale;
      } else {  // MODE 3 — region is uniform per block (bn multiple of 128)
        if (bn < 2048) {
          f16* C = (f16*)Cout;
          const float* bias = (bn < 1024) ? b0 : (b1 - 1024);
          const float bb = bias[col];
#pragma unroll
          for (int r = 0; r < 4; r++)
            C[(size_t)(row0 + r) * 2048 + col] = (f16)(acc[i][j][r] + bb);
        } else {
          f16* C = (f16*)Cout2;
          const float bb = b2[col - 2048];
          f16x4 o;
#pragma unroll
          for (int r = 0; r < 4; r++) o[r] = (f16)(acc[i][j][r] + bb);
          *(f16x4*)(C + (size_t)(col - 2048) * MTOT + row0) = o;
        }
      }
    }
  }
}

// ---------------------------------------------------------------------------
// Per-row exact top-k(1638) + softmax (block-level version — best measured).
// Quantized 2048-bin histogram -> threshold bin -> exact tie refinement on
// fp32 value + index. Reads fp32 S (pitch 2048), writes compact f16 P.
// ---------------------------------------------------------------------------
__global__ __launch_bounds__(256) void topk_softmax_kernel(
    const float* __restrict__ S, f16* __restrict__ P) {
  const size_t row = blockIdx.x;
  const float* srow = S + row * 2048;
  f16* prow = P + row * 2048;
  const int t = threadIdx.x;
  const int lane = t & 63;
  const int wave = t >> 6;

  float v[8];
  float4 f0 = ((const float4*)srow)[2 * t];
  float4 f1 = ((const float4*)srow)[2 * t + 1];
  v[0] = f0.x; v[1] = f0.y; v[2] = f0.z; v[3] = f0.w;
  v[4] = f1.x; v[5] = f1.y; v[6] = f1.z; v[7] = f1.w;

  __shared__ float wlo[4], whi[4];
  __shared__ float wf[4];
  __shared__ int wagg[4];
  __shared__ int hist[2048];
  __shared__ float cval[128];
  __shared__ int cidx[128];
  __shared__ int cnum;
  __shared__ int sh_thr, sh_want;

  float lo = v[0], hi = v[0];
#pragma unroll
  for (int j = 1; j < 8; j++) { lo = fminf(lo, v[j]); hi = fmaxf(hi, v[j]); }
#pragma unroll
  for (int off = 32; off > 0; off >>= 1) {
    lo = fminf(lo, __shfl_xor(lo, off, 64));
    hi = fmaxf(hi, __shfl_xor(hi, off, 64));
  }
  if (lane == 0) { wlo[wave] = lo; whi[wave] = hi; }
  if (t == 0) cnum = 0;
  ((int4*)hist)[2 * t] = (int4){0, 0, 0, 0};
  ((int4*)hist)[2 * t + 1] = (int4){0, 0, 0, 0};
  __syncthreads();
  lo = fminf(fminf(wlo[0], wlo[1]), fminf(wlo[2], wlo[3]));
  hi = fmaxf(fmaxf(whi[0], whi[1]), fmaxf(whi[2], whi[3]));

  if (hi == lo) {
    const float w = 1.0f / (float)KKEEP;
    f16x8 o;
#pragma unroll
    for (int j = 0; j < 8; j++) o[j] = (f16)((t * 8 + j < KKEEP) ? w : 0.f);
    *(f16x8*)(prow + t * 8) = o;
    return;
  }

  const float qs = 2048.0f / (hi - lo);
  int key[8];
#pragma unroll
  for (int j = 0; j < 8; j++) {
    int k = (int)((v[j] - lo) * qs);
    key[j] = (k > 2047) ? 2047 : k;
  }
#pragma unroll
  for (int j = 0; j < 8; j++) atomicAdd(&hist[key[j]], 1);
  __syncthreads();

  int4 h0 = ((const int4*)hist)[2 * t];
  int4 h1 = ((const int4*)hist)[2 * t + 1];
  int h[8] = {h0.x, h0.y, h0.z, h0.w, h1.x, h1.y, h1.z, h1.w};
  int s[8];
  s[7] = h[7];
#pragma unroll
  for (int j = 6; j >= 0; j--) s[j] = s[j + 1] + h[j];
  const int partial = s[0];
  int sfx = partial;
#pragma unroll
  for (int off = 1; off < 64; off <<= 1) {
    int o = __shfl_down(sfx, off, 64);
    sfx += (lane + off < 64) ? o : 0;
  }
  if (lane == 0) wagg[wave] = sfx;
  __syncthreads();
  int hiw = 0;
#pragma unroll
  for (int w = 0; w < 4; w++) hiw += (w > wave) ? wagg[w] : 0;
  const int base = (sfx - partial) + hiw;
#pragma unroll
  for (int j = 0; j < 8; j++) {
    const int cum = s[j] + base;
    const int above = cum - h[j];
    if (cum >= KKEEP && above < KKEEP) {
      sh_thr = 8 * t + j;
      sh_want = KKEEP - above;
    }
  }
  __syncthreads();
  const int thr = sh_thr;
  const int wantin = sh_want;

#pragma unroll
  for (int j = 0; j < 8; j++) {
    if (key[j] == thr) {
      int slot = atomicAdd(&cnum, 1);
      if (slot < 128) { cval[slot] = v[j]; cidx[slot] = t * 8 + j; }
    }
  }
  __syncthreads();
  const int n = (cnum < 128) ? cnum : 128;

  float e[8];
  float lsum = 0.f;
#pragma unroll
  for (int j = 0; j < 8; j++) {
    bool kept;
    if (key[j] > thr) {
      kept = true;
    } else if (key[j] < thr) {
      kept = false;
    } else {
      const int myidx = t * 8 + j;
      int rank = 0;
      for (int c = 0; c < n; c++) {
        const float cv = cval[c];
        rank += (cv > v[j] || (cv == v[j] && cidx[c] < myidx)) ? 1 : 0;
      }
      kept = rank < wantin;
    }
    e[j] = kept ? __expf(v[j] - hi) : 0.f;
    lsum += e[j];
  }
#pragma unroll
  for (int off = 32; off > 0; off >>= 1) lsum += __shfl_xor(lsum, off, 64);
  if (lane == 0) wf[wave] = lsum;
  __syncthreads();
  const float inv = 1.0f / (wf[0] + wf[1] + wf[2] + wf[3]);

  f16x8 o;
#pragma unroll
  for (int j = 0; j < 8; j++) o[j] = (f16)(e[j] * inv);
  *(f16x8*)(prow + t * 8) = o;
}

// ---------------------------------------------------------------------------
// launch — 5 dispatches.
// Workspace (peak 224 MiB): [qkb 64M][vtb 32M][S fp32 128M]
//   qkb = [16384][2048] f16: cols 0-1023 Q, 1024-2047 K.
//   xb (32M) + wqkv (6M) aliased into S's span (dead before S written).
//   Pc (compact f16 P, 64M) aliased over qkb (dead after score GEMM).
// ---------------------------------------------------------------------------
extern "C" void kernel_launch(void* const* d_in, const int* in_sizes, int n_in,
                              void* d_out, int out_size, void* d_ws, size_t ws_size,
                              hipStream_t stream) {
  (void)in_sizes; (void)n_in; (void)out_size; (void)ws_size;
  const float* x = (const float*)d_in[0];
  const float* Wq = (const float*)d_in[1];
  const float* bq = (const float*)d_in[2];
  const float* Wk = (const float*)d_in[3];
  const float* bk = (const float*)d_in[4];
  const float* Wv = (const float*)d_in[5];
  const float* bv = (const float*)d_in[6];
  float* out = (float*)d_out;

  char* ws = (char*)d_ws;
  f16* qkb = (f16*)(ws + 0);           // [16384][2048] f16  67,108,864 B
  f16* vtb = (f16*)(ws + 67108864);    // [1024][16384] f16 (V^T)
  float* S = (float*)(ws + 100663296); // [8][2048][2048] fp32 (134,217,728 B)
  // --- aliased into S's span; dead before S is first written ---
  f16* xb = (f16*)(ws + 100663296);    // [16384][1024]
  f16* wqkv = (f16*)(ws + 134217728);  // [3072][1024] (Wq|Wk|Wv rows)
  // --- aliased over qkb; dead after the score GEMM ---
  f16* Pc = (f16*)(ws + 0);            // [8][2048][2048] f16 compact

  // 1) conversions (single dispatch)
  cvt_all<<<(X4 + 3 * W4 + 255) / 256, 256, 0, stream>>>(x, Wq, Wk, Wv, xb, wqkv);

  // 2) fused QKV projection: cols 0-2047 -> qkb, cols 2048-3071 -> vtb (transposed)
  gemm_bt<3><<<dim3(MTOT / 128, 3072 / 128, 1), 256, 0, stream>>>(
      xb, wqkv, bq, bk, bv, qkb, vtb, CC, CC, CC, 0, 1.f, 0, 0, 0);

  // 3) scores S[b] = Q[b] K[b]^T / 32  (fp32 out; overwrites dead xb/wqkv)
  gemm_bt<0><<<dim3(NN / 128, NN / 128, BB), 256, 0, stream>>>(
      qkb, qkb + 1024, nullptr, nullptr, nullptr, S, nullptr, CC, 2048, 2048, NN,
      1.f / 32.f, (long)NN * 2048, (long)NN * 2048, (long)NN * NN);

  // 4) exact top-k + softmax -> compact P f16 (over dead qkb)
  topk_softmax_kernel<<<MTOT, 256, 0, stream>>>(S, Pc);

  // 5) O[b] = P[b] Vt[b]^T  (fp32 out to d_out)
  gemm_bt<0><<<dim3(NN / 128, CC / 128, BB), 256, 0, stream>>>(
      Pc, vtb, nullptr, nullptr, nullptr, out, nullptr, NN, NN, MTOT, CC, 1.f,
      (long)NN * NN, (long)NN, (long)NN * CC);
}